// Round 2
// baseline (1169.479 us; speedup 1.0000x reference)
//
#include <hip/hip_runtime.h>
#include <cstdint>

using u16 = unsigned short;
using u32 = unsigned int;

typedef short s16x8 __attribute__((ext_vector_type(8)));   // 8 bf16 (4 VGPRs)
typedef float f32x4 __attribute__((ext_vector_type(4)));

__device__ __forceinline__ u16 f2bf(float f) {  // f32 -> bf16 RNE
  u32 u = __float_as_uint(f);
  return (u16)((u + 0x7fffu + ((u >> 16) & 1u)) >> 16);
}

__device__ __forceinline__ void gld16(const void* g, void* l) {
  __builtin_amdgcn_global_load_lds(
      (const __attribute__((address_space(1))) u32*)g,
      (__attribute__((address_space(3))) u32*)l, 16, 0, 0);
}

#define MFMA(a, b, c) __builtin_amdgcn_mfma_f32_16x16x32_bf16((a), (b), (c), 0, 0, 0)

// ---------------------------------------------------------------------------
// Generic NT GEMM: C[M,N] = A[M,K] @ B[N,K]^T (+bias[col])
// OUT_MODE: 0 = f32 row-major ldOut, 1 = bf16 row-major ldOut,
//           2 = bf16 transposed per-batch: out[(b*N+col)*S + (row - b*S)], S=ldOut
// 128x128 tile, BK=32, 4 waves (2x2), global_load_lds staging (m97 pattern).
// ---------------------------------------------------------------------------
template<int OUT_MODE, bool HAS_BIAS>
__global__ __launch_bounds__(256, 2)
void gemm_nt(const u16* __restrict__ A, const u16* __restrict__ B,
             const float* __restrict__ bias, void* __restrict__ C,
             int M, int N, int K, int ldOut)
{
  __shared__ __align__(16) u16 smem[17408];  // As[128*32] | Bs[128*32]; epi: ct[128][136]
  u16* As = smem;
  u16* Bs = smem + 4096;
  const int tid = threadIdx.x, wv = tid >> 6, ln = tid & 63;
  const int wm = wv >> 1, wn = wv & 1;
  const long m0 = (long)blockIdx.y * 128, n0 = (long)blockIdx.x * 128;

  f32x4 acc[4][4] = {};
  for (int k0 = 0; k0 < K; k0 += 32) {
    #pragma unroll
    for (int j = 0; j < 2; j++) {
      const int ub = j*256 + wv*64, u = ub + ln;
      gld16(A + (m0 + (u >> 2)) * K + k0 + (u & 3) * 8, As + ub * 8);
    }
    #pragma unroll
    for (int j = 0; j < 2; j++) {
      const int ub = j*256 + wv*64, u = ub + ln;
      gld16(B + (n0 + (u >> 2)) * K + k0 + (u & 3) * 8, Bs + ub * 8);
    }
    __syncthreads();
    {
      s16x8 af[4], bf[4];
      const int kk = (ln >> 4) * 8;
      #pragma unroll
      for (int i = 0; i < 4; i++) af[i] = *(const s16x8*)&As[(wm*64 + i*16 + (ln & 15)) * 32 + kk];
      #pragma unroll
      for (int i = 0; i < 4; i++) bf[i] = *(const s16x8*)&Bs[(wn*64 + i*16 + (ln & 15)) * 32 + kk];
      #pragma unroll
      for (int i = 0; i < 4; i++)
        #pragma unroll
        for (int j = 0; j < 4; j++)
          acc[i][j] = MFMA(af[i], bf[j], acc[i][j]);
    }
    __syncthreads();
  }

  if constexpr (OUT_MODE == 2) {
    u16* ct = smem;  // [128 col][136 row] bf16
    #pragma unroll
    for (int i = 0; i < 4; i++)
      #pragma unroll
      for (int j = 0; j < 4; j++)
        #pragma unroll
        for (int jj = 0; jj < 4; jj++) {
          const int cl = wn*64 + j*16 + (ln & 15);
          const int rl = wm*64 + i*16 + (ln >> 4) * 4 + jj;
          float v = acc[i][j][jj];
          if constexpr (HAS_BIAS) v += bias[n0 + cl];
          ct[cl * 136 + rl] = f2bf(v);
        }
    __syncthreads();
    const long S = ldOut;
    const long bb = m0 / S;                 // batch index (tile never crosses: S % 128 == 0)
    u16* T = (u16*)C + bb * (long)(N - 1) * S;
    #pragma unroll
    for (int t = 0; t < 8; t++) {
      const int u = t*256 + tid;
      const int cl = u >> 4, r8 = (u & 15) * 8;
      *(s16x8*)&T[(n0 + cl) * S + (m0 + r8)] = *(const s16x8*)&ct[cl * 136 + r8];
    }
  } else {
    #pragma unroll
    for (int i = 0; i < 4; i++)
      #pragma unroll
      for (int jj = 0; jj < 4; jj++) {
        const long r = m0 + wm*64 + i*16 + (ln >> 4) * 4 + jj;
        #pragma unroll
        for (int j = 0; j < 4; j++) {
          const long col = n0 + wn*64 + j*16 + (ln & 15);
          float v = acc[i][j][jj];
          if constexpr (HAS_BIAS) v += bias[col];
          if constexpr (OUT_MODE == 0) ((float*)C)[r * ldOut + col] = v;
          else                         ((u16*)C)[r * ldOut + col] = f2bf(v);
        }
      }
  }
}

// ---------------------------------------------------------------------------
// Pass 1 (per batch-group of 4): per (b,h, 64-row q-tile): S = Q@K^T,
// row softmax over Hl=256 (mask-shift trick), out_v = P @ VlT^T.
// Writes out IN PLACE over this block's own Q slice (read-complete before
// the store; slice touched by no other block). attn_l must run first.
// ---------------------------------------------------------------------------
__global__ __launch_bounds__(256, 2)
void attn_v(u16* __restrict__ Q, const u16* __restrict__ Kw,
            const u16* __restrict__ VlT, const int* __restrict__ mask_v,
            const int* __restrict__ mask_l, const int* __restrict__ anylp,
            int b_base)
{
  __shared__ __align__(16) u16 As[64*72];
  __shared__ __align__(16) u16 Bs[256*72];
  __shared__ __align__(16) u16 Ps[64*264];
  __shared__ float red[256];

  const int qt = blockIdx.x;
  const int bl = blockIdx.y >> 3, h = blockIdx.y & 7;
  const int b = b_base + bl;
  const int tid = threadIdx.x, wv = tid >> 6, ln = tid & 63;

  u16* Qb = Q + (long)(bl*4096 + qt*64) * 2048 + h*256;     // group-local
  const u16* Kb = Kw + (long)(b*256) * 2048 + h*256;        // global
  const u16* Vb = VlT + (long)(b*8 + h) * 65536;            // global

  const int al = anylp[b];
  float mlf[4], rf[4][4];
  #pragma unroll
  for (int j = 0; j < 4; j++)
    mlf[j] = mask_l[b*256 + wv*64 + j*16 + (ln & 15)] ? 1.f : 0.f;
  #pragma unroll
  for (int i = 0; i < 4; i++)
    #pragma unroll
    for (int jj = 0; jj < 4; jj++)
      rf[i][jj] = (al && mask_v[b*4096 + qt*64 + i*16 + (ln >> 4)*4 + jj]) ? 1.f : 0.f;

  // ---- S = Q @ K^T : [64 q][256 k], wave owns k-slice wv*64
  f32x4 acc[4][4] = {};
  for (int d0 = 0; d0 < 256; d0 += 64) {
    #pragma unroll
    for (int j = 0; j < 2; j++) {
      const int u = j*256 + tid, r = u >> 3, c = (u & 7) * 8;
      *(s16x8*)&As[r*72 + c] = *(const s16x8*)(Qb + (long)r*2048 + d0 + c);
    }
    #pragma unroll
    for (int j = 0; j < 8; j++) {
      const int u = j*256 + tid, r = u >> 3, c = (u & 7) * 8;
      *(s16x8*)&Bs[r*72 + c] = *(const s16x8*)(Kb + (long)r*2048 + d0 + c);
    }
    __syncthreads();
    #pragma unroll
    for (int ks = 0; ks < 2; ks++) {
      s16x8 af[4], bf[4];
      const int kk = ks*32 + (ln >> 4) * 8;
      #pragma unroll
      for (int i = 0; i < 4; i++) af[i] = *(const s16x8*)&As[(i*16 + (ln & 15))*72 + kk];
      #pragma unroll
      for (int j = 0; j < 4; j++) bf[j] = *(const s16x8*)&Bs[(wv*64 + j*16 + (ln & 15))*72 + kk];
      #pragma unroll
      for (int i = 0; i < 4; i++)
        #pragma unroll
        for (int j = 0; j < 4; j++)
          acc[i][j] = MFMA(af[i], bf[j], acc[i][j]);
    }
    __syncthreads();
  }

  // ---- row softmax (mask-shift trick: E = rf ? maskl*exp(S) : 1)
  #pragma unroll
  for (int i = 0; i < 4; i++)
    #pragma unroll
    for (int j = 0; j < 4; j++)
      #pragma unroll
      for (int jj = 0; jj < 4; jj++) {
        const float s = acc[i][j][jj];
        acc[i][j][jj] = (rf[i][jj] != 0.f) ? mlf[j] * __expf(s) : 1.0f;
      }
  #pragma unroll
  for (int i = 0; i < 4; i++)
    #pragma unroll
    for (int jj = 0; jj < 4; jj++) {
      float t = acc[i][0][jj] + acc[i][1][jj] + acc[i][2][jj] + acc[i][3][jj];
      t += __shfl_xor(t, 1); t += __shfl_xor(t, 2);
      t += __shfl_xor(t, 4); t += __shfl_xor(t, 8);
      if ((ln & 15) == 0) red[wv*64 + i*16 + (ln >> 4)*4 + jj] = t;
    }
  __syncthreads();
  float inv[4][4];
  #pragma unroll
  for (int i = 0; i < 4; i++)
    #pragma unroll
    for (int jj = 0; jj < 4; jj++) {
      const int r = i*16 + (ln >> 4)*4 + jj;
      inv[i][jj] = 1.0f / (red[r] + red[64 + r] + red[128 + r] + red[192 + r]);
    }
  #pragma unroll
  for (int i = 0; i < 4; i++)
    #pragma unroll
    for (int j = 0; j < 4; j++)
      #pragma unroll
      for (int jj = 0; jj < 4; jj++)
        Ps[(i*16 + (ln >> 4)*4 + jj)*264 + wv*64 + j*16 + (ln & 15)] =
            f2bf(acc[i][j][jj] * inv[i][jj]);
  __syncthreads();

  // ---- out_v = P @ VlT^T : [64 q][256 d], wave owns d-slice wv*64
  f32x4 acc2[4][4] = {};
  for (int c0 = 0; c0 < 256; c0 += 64) {
    #pragma unroll
    for (int j = 0; j < 8; j++) {
      const int u = j*256 + tid, r = u >> 3, c = (u & 7) * 8;
      *(s16x8*)&Bs[r*72 + c] = *(const s16x8*)(Vb + (long)r*256 + c0 + c);
    }
    __syncthreads();
    #pragma unroll
    for (int ks = 0; ks < 2; ks++) {
      s16x8 af[4], bf[4];
      const int kk = ks*32 + (ln >> 4) * 8;
      #pragma unroll
      for (int i = 0; i < 4; i++) af[i] = *(const s16x8*)&Ps[(i*16 + (ln & 15))*264 + c0 + kk];
      #pragma unroll
      for (int j = 0; j < 4; j++) bf[j] = *(const s16x8*)&Bs[(wv*64 + j*16 + (ln & 15))*72 + kk];
      #pragma unroll
      for (int i = 0; i < 4; i++)
        #pragma unroll
        for (int j = 0; j < 4; j++)
          acc2[i][j] = MFMA(af[i], bf[j], acc2[i][j]);
    }
    __syncthreads();
  }
  // in-place store over own Q slice
  #pragma unroll
  for (int i = 0; i < 4; i++)
    #pragma unroll
    for (int j = 0; j < 4; j++)
      #pragma unroll
      for (int jj = 0; jj < 4; jj++)
        Qb[(long)(i*16 + (ln >> 4)*4 + jj)*2048 + wv*64 + j*16 + (ln & 15)] =
            f2bf(acc2[i][j][jj]);
}

// ---------------------------------------------------------------------------
// Pass 2 (per batch-group of 4): per (b,h, 64-row k_l-tile): loop q-chunks:
//   S^T = K_tile @ Q_chunk^T, E = colflag ? maskv*exp(S) : 1,
//   accumulate rowsumE and out_l += E @ VvT^T; normalize at end.
// Writes ol[(b*256+k)*2048 + h*256+d] bf16 (global buffer).
// ---------------------------------------------------------------------------
__global__ __launch_bounds__(256, 2)
void attn_l(const u16* __restrict__ Q, const u16* __restrict__ Kw,
            const u16* __restrict__ VvT, const int* __restrict__ mask_v,
            const int* __restrict__ mask_l, const int* __restrict__ anyvp,
            u16* __restrict__ ol, int b_base)
{
  __shared__ __align__(16) u16 Ks[64*264];
  __shared__ __align__(16) u16 Vs[256*72];
  __shared__ __align__(16) u16 Es[64*72];
  __shared__ float red[256];
  __shared__ float mvf_s[64];
  u16* Qs = Vs;   // [64][72] overlay (disjoint lifetime within a chunk)

  const int kt = blockIdx.x;
  const int bl = blockIdx.y >> 3, h = blockIdx.y & 7;
  const int b = b_base + bl;
  const int tid = threadIdx.x, wv = tid >> 6, ln = tid & 63;

  const u16* Qb  = Q + (long)(bl*4096) * 2048 + h*256;            // group-local
  const u16* Kb  = Kw + (long)(b*256 + kt*64) * 2048 + h*256;     // global
  const u16* Vvb = VvT + (long)(bl*8 + h) * (256L*4096);          // group-local

  // stage K tile [64][256] -> Ks (loop-invariant)
  #pragma unroll
  for (int j = 0; j < 8; j++) {
    const int u = j*256 + tid, r = u >> 5, c = (u & 31) * 8;
    *(s16x8*)&Ks[r*264 + c] = *(const s16x8*)(Kb + (long)r*2048 + c);
  }
  const int av = anyvp[b];
  float crf[4][4];
  #pragma unroll
  for (int i = 0; i < 4; i++)
    #pragma unroll
    for (int jj = 0; jj < 4; jj++)
      crf[i][jj] = (av && mask_l[b*256 + kt*64 + i*16 + (ln >> 4)*4 + jj]) ? 1.f : 0.f;

  float rsum[4][4] = {};
  f32x4 pacc[4][4] = {};

  #pragma unroll 1
  for (int qc = 0; qc < 4096; qc += 64) {
    if (tid < 64) mvf_s[tid] = mask_v[b*4096 + qc + tid] ? 1.f : 0.f;
    // ---- S^T chunk [64 k][64 q]; wave owns q-slice wv*16
    f32x4 sacc[4] = {};
    #pragma unroll 1
    for (int d0 = 0; d0 < 256; d0 += 64) {
      #pragma unroll
      for (int j = 0; j < 2; j++) {
        const int u = j*256 + tid, r = u >> 3, c = (u & 7) * 8;
        *(s16x8*)&Qs[r*72 + c] = *(const s16x8*)(Qb + (long)(qc + r)*2048 + d0 + c);
      }
      __syncthreads();
      #pragma unroll
      for (int ks = 0; ks < 2; ks++) {
        s16x8 af[4], bq;
        const int kk = ks*32 + (ln >> 4) * 8;
        #pragma unroll
        for (int i = 0; i < 4; i++) af[i] = *(const s16x8*)&Ks[(i*16 + (ln & 15))*264 + d0 + kk];
        bq = *(const s16x8*)&Qs[(wv*16 + (ln & 15))*72 + kk];
        #pragma unroll
        for (int i = 0; i < 4; i++) sacc[i] = MFMA(af[i], bq, sacc[i]);
      }
      __syncthreads();
    }
    // ---- E + rowsum + bounce to LDS
    const float mvf = mvf_s[wv*16 + (ln & 15)];
    #pragma unroll
    for (int i = 0; i < 4; i++)
      #pragma unroll
      for (int jj = 0; jj < 4; jj++) {
        const float x = (crf[i][jj] != 0.f) ? mvf * __expf(sacc[i][jj]) : 1.0f;
        float t = x;
        t += __shfl_xor(t, 1); t += __shfl_xor(t, 2);
        t += __shfl_xor(t, 4); t += __shfl_xor(t, 8);
        rsum[i][jj] += t;
        Es[(i*16 + (ln >> 4)*4 + jj)*72 + wv*16 + (ln & 15)] = f2bf(x);
      }
    __syncthreads();
    // ---- stage VvT [256 d][64 q] -> Vs ; out_l += E @ Vs^T
    #pragma unroll
    for (int j = 0; j < 8; j++) {
      const int u = j*256 + tid, r = u >> 3, c = (u & 7) * 8;
      *(s16x8*)&Vs[r*72 + c] = *(const s16x8*)(Vvb + (long)r*4096 + qc + c);
    }
    __syncthreads();
    #pragma unroll
    for (int ks = 0; ks < 2; ks++) {
      s16x8 ae[4], bv[4];
      const int kk = ks*32 + (ln >> 4) * 8;
      #pragma unroll
      for (int i = 0; i < 4; i++) ae[i] = *(const s16x8*)&Es[(i*16 + (ln & 15))*72 + kk];
      #pragma unroll
      for (int j = 0; j < 4; j++) bv[j] = *(const s16x8*)&Vs[(wv*64 + j*16 + (ln & 15))*72 + kk];
      #pragma unroll
      for (int i = 0; i < 4; i++)
        #pragma unroll
        for (int j = 0; j < 4; j++)
          pacc[i][j] = MFMA(ae[i], bv[j], pacc[i][j]);
    }
    __syncthreads();
  }

  #pragma unroll
  for (int i = 0; i < 4; i++)
    #pragma unroll
    for (int jj = 0; jj < 4; jj++)
      if ((ln & 15) == 0) red[wv*64 + i*16 + (ln >> 4)*4 + jj] = rsum[i][jj];
  __syncthreads();
  u16* olb = ol + (long)(b*256 + kt*64) * 2048 + h*256;
  #pragma unroll
  for (int i = 0; i < 4; i++)
    #pragma unroll
    for (int jj = 0; jj < 4; jj++) {
      const int r = i*16 + (ln >> 4)*4 + jj;
      const float invv = 1.0f / (red[r] + red[64 + r] + red[128 + r] + red[192 + r]);
      #pragma unroll
      for (int j = 0; j < 4; j++)
        olb[(long)r*2048 + wv*64 + j*16 + (ln & 15)] = f2bf(pacc[i][j][jj] * invv);
    }
}

// ---------------------------------------------------------------------------
// small utility kernels
// ---------------------------------------------------------------------------
__global__ void cvt_bf16_k(const float* __restrict__ x, u16* __restrict__ y, long n4) {
  const long i = (long)blockIdx.x * 256 + threadIdx.x;
  if (i < n4) {
    const float4 v = ((const float4*)x)[i];
    u32 lo = (u32)f2bf(v.x) | ((u32)f2bf(v.y) << 16);
    u32 hi = (u32)f2bf(v.z) | ((u32)f2bf(v.w) << 16);
    ((uint2*)y)[i] = make_uint2(lo, hi);
  }
}

__global__ void transpose_w(const float* __restrict__ W, u16* __restrict__ WT,
                            int K, int N, float scale) {
  __shared__ float t[64][65];
  const int k0 = blockIdx.y * 64, n0 = blockIdx.x * 64;
  const int tid = threadIdx.x;
  #pragma unroll
  for (int i = 0; i < 16; i++) {
    const int u = i*256 + tid, r = u >> 6, c = u & 63;
    t[r][c] = W[(long)(k0 + r) * N + n0 + c];
  }
  __syncthreads();
  #pragma unroll
  for (int i = 0; i < 16; i++) {
    const int u = i*256 + tid, r = u >> 6, c = u & 63;
    WT[(long)(n0 + r) * K + k0 + c] = f2bf(t[c][r] * scale);
  }
}

__global__ void scale_bias_k(const float* __restrict__ x, float* __restrict__ y,
                             int n, float s) {
  const int i = blockIdx.x * 256 + threadIdx.x;
  if (i < n) y[i] = x[i] * s;
}

__global__ void any_mask_k(const int* __restrict__ mv, const int* __restrict__ ml,
                           int* __restrict__ anyv, int* __restrict__ anyl) {
  __shared__ int s[256];
  const int b = blockIdx.x, t = threadIdx.x;
  int a = 0;
  for (int i = t; i < 4096; i += 256) a |= mv[b*4096 + i];
  s[t] = a; __syncthreads();
  for (int o = 128; o > 0; o >>= 1) { if (t < o) s[t] |= s[t + o]; __syncthreads(); }
  if (t == 0) anyv[b] = s[0] ? 1 : 0;
  __syncthreads();
  s[t] = ml[b*256 + t]; __syncthreads();
  for (int o = 128; o > 0; o >>= 1) { if (t < o) s[t] |= s[t + o]; __syncthreads(); }
  if (t == 0) anyl[b] = s[0] ? 1 : 0;
}

// ---------------------------------------------------------------------------
extern "C" void kernel_launch(void* const* d_in, const int* in_sizes, int n_in,
                              void* d_out, int out_size, void* d_ws, size_t ws_size,
                              hipStream_t stream)
{
  (void)in_sizes; (void)n_in; (void)out_size; (void)ws_size;
  const float* v   = (const float*)d_in[0];
  const float* l   = (const float*)d_in[1];
  const int*   mv  = (const int*)d_in[2];
  const int*   ml  = (const int*)d_in[3];
  const float* Wq  = (const float*)d_in[4];
  const float* bq  = (const float*)d_in[5];
  const float* Wk  = (const float*)d_in[6];
  const float* bk  = (const float*)d_in[7];
  const float* Wvv = (const float*)d_in[8];
  const float* bvv = (const float*)d_in[9];
  const float* Wvl = (const float*)d_in[10];
  const float* bvl = (const float*)d_in[11];
  const float* Wov = (const float*)d_in[12];
  const float* bov = (const float*)d_in[13];
  const float* Wol = (const float*)d_in[14];
  const float* bol = (const float*)d_in[15];

  char* w = (char*)d_ws;
  auto alloc = [&](size_t bytes) { char* p = w; w += (bytes + 255) & ~(size_t)255; return p; };
  // global (both groups):                                    bytes
  u16*   l_bf = (u16*)alloc(1572864ull * 2);               //   3.1M
  u16*   WqT  = (u16*)alloc(2048ull*256*2);                //   1.0M
  u16*   WkT  = (u16*)alloc(2048ull*768*2);                //   3.1M
  u16*   WvvT = (u16*)alloc(2048ull*256*2);                //   1.0M
  u16*   WvlT = (u16*)alloc(2048ull*768*2);                //   3.1M
  u16*   WovT = (u16*)alloc(256ull*2048*2);                //   1.0M
  u16*   WolT = (u16*)alloc(768ull*2048*2);                //   3.1M
  float* bq_s = (float*)alloc(2048*4);
  int*   anyv = (int*)alloc(256);
  int*   anyl = (int*)alloc(256);
  u16*   Kw   = (u16*)alloc(4194304ull * 2);               //   8.4M  [b*256+k][2048]
  u16*   VlT  = (u16*)alloc(4194304ull * 2);               //   8.4M  [b,h,d=256][k=256]
  u16*   ol   = (u16*)alloc(4194304ull * 2);               //   8.4M  [b*256+k][2048]
  // per-group (4 batches), reused across the 2 groups:
  u16*   v_bf = (u16*)alloc(4194304ull * 2);               //   8.4M  [16384][256]
  u16*   Qw   = (u16*)alloc(33554432ull * 2);              //  67.1M  [16384][2048]; becomes ov in place
  u16*   VvT  = (u16*)alloc(33554432ull * 2);              //  67.1M  [bl,h,d=256][q=4096]
  // total ~184 MB

  const float SCL = 0.0625f;  // 256^-0.5

  // ---- setup (l-side + weights), once
  cvt_bf16_k<<<1536, 256, 0, stream>>>(l, l_bf, 393216);
  transpose_w<<<dim3(32, 4),  256, 0, stream>>>(Wq,  WqT,  256, 2048, SCL);
  transpose_w<<<dim3(32, 12), 256, 0, stream>>>(Wk,  WkT,  768, 2048, 1.0f);
  transpose_w<<<dim3(32, 4),  256, 0, stream>>>(Wvv, WvvT, 256, 2048, 1.0f);
  transpose_w<<<dim3(32, 12), 256, 0, stream>>>(Wvl, WvlT, 768, 2048, 1.0f);
  transpose_w<<<dim3(4, 32),  256, 0, stream>>>(Wov, WovT, 2048, 256, 1.0f);
  transpose_w<<<dim3(12, 32), 256, 0, stream>>>(Wol, WolT, 2048, 768, 1.0f);
  scale_bias_k<<<8, 256, 0, stream>>>(bq, bq_s, 2048, SCL);
  any_mask_k<<<8, 256, 0, stream>>>(mv, ml, anyv, anyl);

  // l-side projections (all 8 batches)
  gemm_nt<1, true><<<dim3(16, 16), 256, 0, stream>>>(l_bf, WkT,  bk,  Kw,  2048, 2048, 768, 2048);
  gemm_nt<2, true><<<dim3(16, 16), 256, 0, stream>>>(l_bf, WvlT, bvl, VlT, 2048, 2048, 768, 256);

  // ---- v-side: two groups of 4 batches
  for (int g = 0; g < 2; g++) {
    const int b0 = 4 * g;
    cvt_bf16_k<<<4096, 256, 0, stream>>>(v + (long)g * 4194304, v_bf, 1048576);
    gemm_nt<1, true><<<dim3(16, 128), 256, 0, stream>>>(v_bf, WqT,  bq_s, Qw,  16384, 2048, 256, 2048);
    gemm_nt<2, true><<<dim3(16, 128), 256, 0, stream>>>(v_bf, WvvT, bvv,  VvT, 16384, 2048, 256, 4096);
    // attn_l FIRST (needs intact Qw); then attn_v overwrites Qw in place with out_v
    attn_l<<<dim3(4, 32),  256, 0, stream>>>(Qw, Kw, VvT, mv, ml, anyv, ol, b0);
    attn_v<<<dim3(64, 32), 256, 0, stream>>>(Qw, Kw, VlT, mv, ml, anyl, b0);
    // out_v projection for this group's rows
    gemm_nt<0, true><<<dim3(2, 128), 256, 0, stream>>>(Qw, WovT, bov,
        (float*)d_out + (long)g * 4194304, 16384, 256, 2048, 256);
  }

  // out_l projection (all 8 batches)
  gemm_nt<0, true><<<dim3(6, 16), 256, 0, stream>>>(ol, WolT, bol,
      (float*)d_out + 8388608, 2048, 768, 2048, 768);
}

// Round 3
// 824.124 us; speedup vs baseline: 1.4191x; 1.4191x over previous
//
#include <hip/hip_runtime.h>
#include <cstdint>

using u16 = unsigned short;
using u32 = unsigned int;

typedef short s16x8 __attribute__((ext_vector_type(8)));   // 8 bf16 (4 VGPRs)
typedef float f32x4 __attribute__((ext_vector_type(4)));

__device__ __forceinline__ u16 f2bf(float f) {  // f32 -> bf16 RNE
  u32 u = __float_as_uint(f);
  return (u16)((u + 0x7fffu + ((u >> 16) & 1u)) >> 16);
}
__device__ __forceinline__ float bf2f(u16 u) {
  return __uint_as_float(((u32)u) << 16);
}

__device__ __forceinline__ void gld16(const void* g, void* l) {
  __builtin_amdgcn_global_load_lds(
      (const __attribute__((address_space(1))) u32*)g,
      (__attribute__((address_space(3))) u32*)l, 16, 0, 0);
}

#define MFMA(a, b, c) __builtin_amdgcn_mfma_f32_16x16x32_bf16((a), (b), (c), 0, 0, 0)

// ---------------------------------------------------------------------------
// Generic NT GEMM: C[M,N] = A[M,K] @ B[N,K]^T (+bias[col])
// OUT_MODE: 0 = f32 row-major ldOut, 1 = bf16 row-major ldOut,
//           2 = bf16 transposed per-batch: out[(b*N+col)*S + (row - b*S)], S=ldOut
// 128x128 tile, BK=32, 4 waves (2x2), global_load_lds staging (m97 pattern).
// ---------------------------------------------------------------------------
template<int OUT_MODE, bool HAS_BIAS>
__global__ __launch_bounds__(256, 2)
void gemm_nt(const u16* __restrict__ A, const u16* __restrict__ B,
             const float* __restrict__ bias, void* __restrict__ C,
             int M, int N, int K, int ldOut)
{
  __shared__ __align__(16) u16 smem[17408];  // As[128*32] | Bs[128*32]; epi: ct[128][136]
  u16* As = smem;
  u16* Bs = smem + 4096;
  const int tid = threadIdx.x, wv = tid >> 6, ln = tid & 63;
  const int wm = wv >> 1, wn = wv & 1;
  const long m0 = (long)blockIdx.y * 128, n0 = (long)blockIdx.x * 128;

  f32x4 acc[4][4] = {};
  for (int k0 = 0; k0 < K; k0 += 32) {
    #pragma unroll
    for (int j = 0; j < 2; j++) {
      const int ub = j*256 + wv*64, u = ub + ln;
      gld16(A + (m0 + (u >> 2)) * K + k0 + (u & 3) * 8, As + ub * 8);
    }
    #pragma unroll
    for (int j = 0; j < 2; j++) {
      const int ub = j*256 + wv*64, u = ub + ln;
      gld16(B + (n0 + (u >> 2)) * K + k0 + (u & 3) * 8, Bs + ub * 8);
    }
    __syncthreads();
    {
      s16x8 af[4], bf[4];
      const int kk = (ln >> 4) * 8;
      #pragma unroll
      for (int i = 0; i < 4; i++) af[i] = *(const s16x8*)&As[(wm*64 + i*16 + (ln & 15)) * 32 + kk];
      #pragma unroll
      for (int i = 0; i < 4; i++) bf[i] = *(const s16x8*)&Bs[(wn*64 + i*16 + (ln & 15)) * 32 + kk];
      #pragma unroll
      for (int i = 0; i < 4; i++)
        #pragma unroll
        for (int j = 0; j < 4; j++)
          acc[i][j] = MFMA(af[i], bf[j], acc[i][j]);
    }
    __syncthreads();
  }

  if constexpr (OUT_MODE == 2) {
    u16* ct = smem;  // [128 col][136 row] bf16
    #pragma unroll
    for (int i = 0; i < 4; i++)
      #pragma unroll
      for (int j = 0; j < 4; j++)
        #pragma unroll
        for (int jj = 0; jj < 4; jj++) {
          const int cl = wn*64 + j*16 + (ln & 15);
          const int rl = wm*64 + i*16 + (ln >> 4) * 4 + jj;
          float v = acc[i][j][jj];
          if constexpr (HAS_BIAS) v += bias[n0 + cl];
          ct[cl * 136 + rl] = f2bf(v);
        }
    __syncthreads();
    const long S = ldOut;
    const long bb = m0 / S;                 // batch index (tile never crosses: S % 128 == 0)
    u16* T = (u16*)C + bb * (long)(N - 1) * S;
    #pragma unroll
    for (int t = 0; t < 8; t++) {
      const int u = t*256 + tid;
      const int cl = u >> 4, r8 = (u & 15) * 8;
      *(s16x8*)&T[(n0 + cl) * S + (m0 + r8)] = *(const s16x8*)&ct[cl * 136 + r8];
    }
  } else {
    #pragma unroll
    for (int i = 0; i < 4; i++)
      #pragma unroll
      for (int jj = 0; jj < 4; jj++) {
        const long r = m0 + wm*64 + i*16 + (ln >> 4) * 4 + jj;
        #pragma unroll
        for (int j = 0; j < 4; j++) {
          const long col = n0 + wn*64 + j*16 + (ln & 15);
          float v = acc[i][j][jj];
          if constexpr (HAS_BIAS) v += bias[col];
          if constexpr (OUT_MODE == 0) ((float*)C)[r * ldOut + col] = v;
          else                         ((u16*)C)[r * ldOut + col] = f2bf(v);
        }
      }
  }
}

// ---------------------------------------------------------------------------
// Pass 1 (per batch-group of 4): per (b,h, 64-row q-tile): S = Q@K^T,
// row softmax over Hl=256 (mask-shift trick), out_v = P @ VlT^T.
// Writes out IN PLACE over this block's own Q slice. attn_l_part runs first.
// ---------------------------------------------------------------------------
__global__ __launch_bounds__(256, 2)
void attn_v(u16* __restrict__ Q, const u16* __restrict__ Kw,
            const u16* __restrict__ VlT, const int* __restrict__ mask_v,
            const int* __restrict__ mask_l, const int* __restrict__ anylp,
            int b_base)
{
  __shared__ __align__(16) u16 As[64*72];
  __shared__ __align__(16) u16 Bs[256*72];
  __shared__ __align__(16) u16 Ps[64*264];
  __shared__ float red[256];

  const int qt = blockIdx.x;
  const int bl = blockIdx.y >> 3, h = blockIdx.y & 7;
  const int b = b_base + bl;
  const int tid = threadIdx.x, wv = tid >> 6, ln = tid & 63;

  u16* Qb = Q + (long)(bl*4096 + qt*64) * 2048 + h*256;     // group-local
  const u16* Kb = Kw + (long)(b*256) * 2048 + h*256;        // global
  const u16* Vb = VlT + (long)(b*8 + h) * 65536;            // global

  const int al = anylp[b];
  float mlf[4], rf[4][4];
  #pragma unroll
  for (int j = 0; j < 4; j++)
    mlf[j] = mask_l[b*256 + wv*64 + j*16 + (ln & 15)] ? 1.f : 0.f;
  #pragma unroll
  for (int i = 0; i < 4; i++)
    #pragma unroll
    for (int jj = 0; jj < 4; jj++)
      rf[i][jj] = (al && mask_v[b*4096 + qt*64 + i*16 + (ln >> 4)*4 + jj]) ? 1.f : 0.f;

  // ---- S = Q @ K^T : [64 q][256 k], wave owns k-slice wv*64
  f32x4 acc[4][4] = {};
  for (int d0 = 0; d0 < 256; d0 += 64) {
    #pragma unroll
    for (int j = 0; j < 2; j++) {
      const int u = j*256 + tid, r = u >> 3, c = (u & 7) * 8;
      *(s16x8*)&As[r*72 + c] = *(const s16x8*)(Qb + (long)r*2048 + d0 + c);
    }
    #pragma unroll
    for (int j = 0; j < 8; j++) {
      const int u = j*256 + tid, r = u >> 3, c = (u & 7) * 8;
      *(s16x8*)&Bs[r*72 + c] = *(const s16x8*)(Kb + (long)r*2048 + d0 + c);
    }
    __syncthreads();
    #pragma unroll
    for (int ks = 0; ks < 2; ks++) {
      s16x8 af[4], bf[4];
      const int kk = ks*32 + (ln >> 4) * 8;
      #pragma unroll
      for (int i = 0; i < 4; i++) af[i] = *(const s16x8*)&As[(i*16 + (ln & 15))*72 + kk];
      #pragma unroll
      for (int j = 0; j < 4; j++) bf[j] = *(const s16x8*)&Bs[(wv*64 + j*16 + (ln & 15))*72 + kk];
      #pragma unroll
      for (int i = 0; i < 4; i++)
        #pragma unroll
        for (int j = 0; j < 4; j++)
          acc[i][j] = MFMA(af[i], bf[j], acc[i][j]);
    }
    __syncthreads();
  }

  // ---- row softmax (mask-shift trick: E = rf ? maskl*exp(S) : 1)
  #pragma unroll
  for (int i = 0; i < 4; i++)
    #pragma unroll
    for (int j = 0; j < 4; j++)
      #pragma unroll
      for (int jj = 0; jj < 4; jj++) {
        const float s = acc[i][j][jj];
        acc[i][j][jj] = (rf[i][jj] != 0.f) ? mlf[j] * __expf(s) : 1.0f;
      }
  #pragma unroll
  for (int i = 0; i < 4; i++)
    #pragma unroll
    for (int jj = 0; jj < 4; jj++) {
      float t = acc[i][0][jj] + acc[i][1][jj] + acc[i][2][jj] + acc[i][3][jj];
      t += __shfl_xor(t, 1); t += __shfl_xor(t, 2);
      t += __shfl_xor(t, 4); t += __shfl_xor(t, 8);
      if ((ln & 15) == 0) red[wv*64 + i*16 + (ln >> 4)*4 + jj] = t;
    }
  __syncthreads();
  float inv[4][4];
  #pragma unroll
  for (int i = 0; i < 4; i++)
    #pragma unroll
    for (int jj = 0; jj < 4; jj++) {
      const int r = i*16 + (ln >> 4)*4 + jj;
      inv[i][jj] = 1.0f / (red[r] + red[64 + r] + red[128 + r] + red[192 + r]);
    }
  #pragma unroll
  for (int i = 0; i < 4; i++)
    #pragma unroll
    for (int j = 0; j < 4; j++)
      #pragma unroll
      for (int jj = 0; jj < 4; jj++)
        Ps[(i*16 + (ln >> 4)*4 + jj)*264 + wv*64 + j*16 + (ln & 15)] =
            f2bf(acc[i][j][jj] * inv[i][jj]);
  __syncthreads();

  // ---- out_v = P @ VlT^T : [64 q][256 d], wave owns d-slice wv*64
  f32x4 acc2[4][4] = {};
  for (int c0 = 0; c0 < 256; c0 += 64) {
    #pragma unroll
    for (int j = 0; j < 8; j++) {
      const int u = j*256 + tid, r = u >> 3, c = (u & 7) * 8;
      *(s16x8*)&Bs[r*72 + c] = *(const s16x8*)(Vb + (long)r*256 + c0 + c);
    }
    __syncthreads();
    #pragma unroll
    for (int ks = 0; ks < 2; ks++) {
      s16x8 af[4], bf[4];
      const int kk = ks*32 + (ln >> 4) * 8;
      #pragma unroll
      for (int i = 0; i < 4; i++) af[i] = *(const s16x8*)&Ps[(i*16 + (ln & 15))*264 + c0 + kk];
      #pragma unroll
      for (int j = 0; j < 4; j++) bf[j] = *(const s16x8*)&Bs[(wv*64 + j*16 + (ln & 15))*72 + kk];
      #pragma unroll
      for (int i = 0; i < 4; i++)
        #pragma unroll
        for (int j = 0; j < 4; j++)
          acc2[i][j] = MFMA(af[i], bf[j], acc2[i][j]);
    }
    __syncthreads();
  }
  // in-place store over own Q slice
  #pragma unroll
  for (int i = 0; i < 4; i++)
    #pragma unroll
    for (int j = 0; j < 4; j++)
      #pragma unroll
      for (int jj = 0; jj < 4; jj++)
        Qb[(long)(i*16 + (ln >> 4)*4 + jj)*2048 + wv*64 + j*16 + (ln & 15)] =
            f2bf(acc2[i][j][jj]);
}

// ---------------------------------------------------------------------------
// Pass 2a (split-q partials): grid (split s=0..7, kt=0..3, bh=0..31).
// Each block: K-tile [64 k] x q in [s*512, s*512+512):
//   S^T = K_tile @ Q_chunk^T, E = colflag ? maskv*exp(S) : 1,
//   accumulate partial rowsumE (f32) and partial E @ VvT^T (bf16) to ws.
// ---------------------------------------------------------------------------
#define NSPLIT 8
__global__ __launch_bounds__(256, 2)
void attn_l_part(const u16* __restrict__ Q, const u16* __restrict__ Kw,
                 const u16* __restrict__ VvT, const int* __restrict__ mask_v,
                 const int* __restrict__ mask_l, const int* __restrict__ anyvp,
                 u16* __restrict__ Pp, float* __restrict__ Rp, int b_base)
{
  __shared__ __align__(16) u16 Ks[64*264];
  __shared__ __align__(16) u16 Vs[256*72];
  __shared__ __align__(16) u16 Es[64*72];
  __shared__ float red[256];
  __shared__ float mvf_s[64];
  u16* Qs = Vs;   // [64][72] overlay (disjoint lifetime within a chunk)

  const int sp = blockIdx.x, kt = blockIdx.y;
  const int bl = blockIdx.z >> 3, h = blockIdx.z & 7;
  const int b = b_base + bl;
  const int tid = threadIdx.x, wv = tid >> 6, ln = tid & 63;

  const u16* Qb  = Q + (long)(bl*4096) * 2048 + h*256;            // group-local
  const u16* Kb  = Kw + (long)(b*256 + kt*64) * 2048 + h*256;     // global
  const u16* Vvb = VvT + (long)(bl*8 + h) * (256L*4096);          // group-local

  // stage K tile [64][256] -> Ks (loop-invariant)
  #pragma unroll
  for (int j = 0; j < 8; j++) {
    const int u = j*256 + tid, r = u >> 5, c = (u & 31) * 8;
    *(s16x8*)&Ks[r*264 + c] = *(const s16x8*)(Kb + (long)r*2048 + c);
  }
  const int av = anyvp[b];
  float crf[4][4];
  #pragma unroll
  for (int i = 0; i < 4; i++)
    #pragma unroll
    for (int jj = 0; jj < 4; jj++)
      crf[i][jj] = (av && mask_l[b*256 + kt*64 + i*16 + (ln >> 4)*4 + jj]) ? 1.f : 0.f;

  float rsum[4][4] = {};
  f32x4 pacc[4][4] = {};

  const int qlo = sp * (4096 / NSPLIT), qhi = qlo + 4096 / NSPLIT;
  #pragma unroll 1
  for (int qc = qlo; qc < qhi; qc += 64) {
    if (tid < 64) mvf_s[tid] = mask_v[b*4096 + qc + tid] ? 1.f : 0.f;
    // ---- S^T chunk [64 k][64 q]; wave owns q-slice wv*16
    f32x4 sacc[4] = {};
    #pragma unroll 1
    for (int d0 = 0; d0 < 256; d0 += 64) {
      #pragma unroll
      for (int j = 0; j < 2; j++) {
        const int u = j*256 + tid, r = u >> 3, c = (u & 7) * 8;
        *(s16x8*)&Qs[r*72 + c] = *(const s16x8*)(Qb + (long)(qc + r)*2048 + d0 + c);
      }
      __syncthreads();
      #pragma unroll
      for (int ks = 0; ks < 2; ks++) {
        s16x8 af[4], bq;
        const int kk = ks*32 + (ln >> 4) * 8;
        #pragma unroll
        for (int i = 0; i < 4; i++) af[i] = *(const s16x8*)&Ks[(i*16 + (ln & 15))*264 + d0 + kk];
        bq = *(const s16x8*)&Qs[(wv*16 + (ln & 15))*72 + kk];
        #pragma unroll
        for (int i = 0; i < 4; i++) sacc[i] = MFMA(af[i], bq, sacc[i]);
      }
      __syncthreads();
    }
    // ---- E + rowsum + bounce to LDS
    const float mvf = mvf_s[wv*16 + (ln & 15)];
    #pragma unroll
    for (int i = 0; i < 4; i++)
      #pragma unroll
      for (int jj = 0; jj < 4; jj++) {
        const float x = (crf[i][jj] != 0.f) ? mvf * __expf(sacc[i][jj]) : 1.0f;
        float t = x;
        t += __shfl_xor(t, 1); t += __shfl_xor(t, 2);
        t += __shfl_xor(t, 4); t += __shfl_xor(t, 8);
        rsum[i][jj] += t;
        Es[(i*16 + (ln >> 4)*4 + jj)*72 + wv*16 + (ln & 15)] = f2bf(x);
      }
    __syncthreads();
    // ---- stage VvT [256 d][64 q] -> Vs ; pacc += E @ Vs^T
    #pragma unroll
    for (int j = 0; j < 8; j++) {
      const int u = j*256 + tid, r = u >> 3, c = (u & 7) * 8;
      *(s16x8*)&Vs[r*72 + c] = *(const s16x8*)(Vvb + (long)r*4096 + qc + c);
    }
    __syncthreads();
    #pragma unroll
    for (int ks = 0; ks < 2; ks++) {
      s16x8 ae[4], bv[4];
      const int kk = ks*32 + (ln >> 4) * 8;
      #pragma unroll
      for (int i = 0; i < 4; i++) ae[i] = *(const s16x8*)&Es[(i*16 + (ln & 15))*72 + kk];
      #pragma unroll
      for (int j = 0; j < 4; j++) bv[j] = *(const s16x8*)&Vs[(wv*64 + j*16 + (ln & 15))*72 + kk];
      #pragma unroll
      for (int i = 0; i < 4; i++)
        #pragma unroll
        for (int j = 0; j < 4; j++)
          pacc[i][j] = MFMA(ae[i], bv[j], pacc[i][j]);
    }
    __syncthreads();
  }

  // ---- write partials
  const long unit = ((long)blockIdx.z * 4 + kt) * NSPLIT + sp;
  u16*   Pb = Pp + unit * 16384;   // [64 k][256 d] bf16
  float* Rb = Rp + unit * 64;      // [64 k] f32
  #pragma unroll
  for (int i = 0; i < 4; i++)
    #pragma unroll
    for (int jj = 0; jj < 4; jj++)
      if ((ln & 15) == 0) red[wv*64 + i*16 + (ln >> 4)*4 + jj] = rsum[i][jj];
  __syncthreads();
  if (tid < 64) Rb[tid] = red[tid] + red[64 + tid] + red[128 + tid] + red[192 + tid];
  #pragma unroll
  for (int i = 0; i < 4; i++)
    #pragma unroll
    for (int jj = 0; jj < 4; jj++) {
      const int r = i*16 + (ln >> 4)*4 + jj;
      #pragma unroll
      for (int j = 0; j < 4; j++)
        Pb[r*256 + wv*64 + j*16 + (ln & 15)] = f2bf(pacc[i][j][jj]);
    }
}

// ---------------------------------------------------------------------------
// Pass 2b (reduce): grid (kt=0..3, bh=0..31). Sums NSPLIT partials,
// normalizes by total rowsum, writes ol[(b*256+k)*2048 + h*256+d] bf16.
// ---------------------------------------------------------------------------
__global__ __launch_bounds__(256, 4)
void attn_l_red(const u16* __restrict__ Pp, const float* __restrict__ Rp,
                u16* __restrict__ ol, int b_base)
{
  __shared__ float rt[64];
  const int kt = blockIdx.x;
  const int bl = blockIdx.y >> 3, h = blockIdx.y & 7;
  const int b = b_base + bl;
  const int tid = threadIdx.x;
  const long ub = ((long)blockIdx.y * 4 + kt) * NSPLIT;

  if (tid < 64) {
    float t = 0.f;
    #pragma unroll
    for (int s = 0; s < NSPLIT; s++) t += Rp[(ub + s) * 64 + tid];
    rt[tid] = 1.0f / t;
  }
  __syncthreads();

  u16* olb = ol + (long)(b*256 + kt*64) * 2048 + h*256;
  #pragma unroll
  for (int it = 0; it < 8; it++) {
    const int idx = it*256 + tid;           // 0..2047 -> (r, 8-wide d chunk)
    const int r = idx >> 5, c8 = (idx & 31) * 8;
    float a[8] = {};
    #pragma unroll
    for (int s = 0; s < NSPLIT; s++) {
      const s16x8 p = *(const s16x8*)&Pp[(ub + s)*16384 + r*256 + c8];
      #pragma unroll
      for (int e = 0; e < 8; e++) a[e] += bf2f((u16)p[e]);
    }
    const float sc = rt[r];
    s16x8 o;
    #pragma unroll
    for (int e = 0; e < 8; e++) o[e] = (short)f2bf(a[e] * sc);
    *(s16x8*)&olb[(long)r*2048 + c8] = o;
  }
}

// ---------------------------------------------------------------------------
// small utility kernels
// ---------------------------------------------------------------------------
__global__ void cvt_bf16_k(const float* __restrict__ x, u16* __restrict__ y, long n4) {
  const long i = (long)blockIdx.x * 256 + threadIdx.x;
  if (i < n4) {
    const float4 v = ((const float4*)x)[i];
    u32 lo = (u32)f2bf(v.x) | ((u32)f2bf(v.y) << 16);
    u32 hi = (u32)f2bf(v.z) | ((u32)f2bf(v.w) << 16);
    ((uint2*)y)[i] = make_uint2(lo, hi);
  }
}

__global__ void transpose_w(const float* __restrict__ W, u16* __restrict__ WT,
                            int K, int N, float scale) {
  __shared__ float t[64][65];
  const int k0 = blockIdx.y * 64, n0 = blockIdx.x * 64;
  const int tid = threadIdx.x;
  #pragma unroll
  for (int i = 0; i < 16; i++) {
    const int u = i*256 + tid, r = u >> 6, c = u & 63;
    t[r][c] = W[(long)(k0 + r) * N + n0 + c];
  }
  __syncthreads();
  #pragma unroll
  for (int i = 0; i < 16; i++) {
    const int u = i*256 + tid, r = u >> 6, c = u & 63;
    WT[(long)(n0 + r) * K + k0 + c] = f2bf(t[c][r] * scale);
  }
}

__global__ void scale_bias_k(const float* __restrict__ x, float* __restrict__ y,
                             int n, float s) {
  const int i = blockIdx.x * 256 + threadIdx.x;
  if (i < n) y[i] = x[i] * s;
}

__global__ void any_mask_k(const int* __restrict__ mv, const int* __restrict__ ml,
                           int* __restrict__ anyv, int* __restrict__ anyl) {
  __shared__ int s[256];
  const int b = blockIdx.x, t = threadIdx.x;
  int a = 0;
  for (int i = t; i < 4096; i += 256) a |= mv[b*4096 + i];
  s[t] = a; __syncthreads();
  for (int o = 128; o > 0; o >>= 1) { if (t < o) s[t] |= s[t + o]; __syncthreads(); }
  if (t == 0) anyv[b] = s[0] ? 1 : 0;
  __syncthreads();
  s[t] = ml[b*256 + t]; __syncthreads();
  for (int o = 128; o > 0; o >>= 1) { if (t < o) s[t] |= s[t + o]; __syncthreads(); }
  if (t == 0) anyl[b] = s[0] ? 1 : 0;
}

// ---------------------------------------------------------------------------
extern "C" void kernel_launch(void* const* d_in, const int* in_sizes, int n_in,
                              void* d_out, int out_size, void* d_ws, size_t ws_size,
                              hipStream_t stream)
{
  (void)in_sizes; (void)n_in; (void)out_size; (void)ws_size;
  const float* v   = (const float*)d_in[0];
  const float* l   = (const float*)d_in[1];
  const int*   mv  = (const int*)d_in[2];
  const int*   ml  = (const int*)d_in[3];
  const float* Wq  = (const float*)d_in[4];
  const float* bq  = (const float*)d_in[5];
  const float* Wk  = (const float*)d_in[6];
  const float* bk  = (const float*)d_in[7];
  const float* Wvv = (const float*)d_in[8];
  const float* bvv = (const float*)d_in[9];
  const float* Wvl = (const float*)d_in[10];
  const float* bvl = (const float*)d_in[11];
  const float* Wov = (const float*)d_in[12];
  const float* bov = (const float*)d_in[13];
  const float* Wol = (const float*)d_in[14];
  const float* bol = (const float*)d_in[15];

  char* w = (char*)d_ws;
  auto alloc = [&](size_t bytes) { char* p = w; w += (bytes + 255) & ~(size_t)255; return p; };
  // global (both groups):
  u16*   l_bf = (u16*)alloc(1572864ull * 2);
  u16*   WqT  = (u16*)alloc(2048ull*256*2);
  u16*   WkT  = (u16*)alloc(2048ull*768*2);
  u16*   WvvT = (u16*)alloc(2048ull*256*2);
  u16*   WvlT = (u16*)alloc(2048ull*768*2);
  u16*   WovT = (u16*)alloc(256ull*2048*2);
  u16*   WolT = (u16*)alloc(768ull*2048*2);
  float* bq_s = (float*)alloc(2048*4);
  int*   anyv = (int*)alloc(256);
  int*   anyl = (int*)alloc(256);
  u16*   Kw   = (u16*)alloc(4194304ull * 2);               //  [b*256+k][2048]
  u16*   VlT  = (u16*)alloc(4194304ull * 2);               //  [b,h,d=256][k=256]
  u16*   ol   = (u16*)alloc(4194304ull * 2);               //  [b*256+k][2048]
  // per-group (4 batches), reused across the 2 groups:
  u16*   v_bf = (u16*)alloc(4194304ull * 2);               //  [16384][256]
  u16*   Qw   = (u16*)alloc(33554432ull * 2);              //  [16384][2048]; becomes ov in place
  u16*   VvT  = (u16*)alloc(33554432ull * 2);              //  [bl,h,d=256][q=4096]
  u16*   Pp   = (u16*)alloc((size_t)32*4*NSPLIT*16384*2);  //  33.6M partial pacc
  float* Rp   = (float*)alloc((size_t)32*4*NSPLIT*64*4);   //  0.26M partial rowsum

  const float SCL = 0.0625f;  // 256^-0.5

  // ---- setup (l-side + weights), once
  cvt_bf16_k<<<1536, 256, 0, stream>>>(l, l_bf, 393216);
  transpose_w<<<dim3(32, 4),  256, 0, stream>>>(Wq,  WqT,  256, 2048, SCL);
  transpose_w<<<dim3(32, 12), 256, 0, stream>>>(Wk,  WkT,  768, 2048, 1.0f);
  transpose_w<<<dim3(32, 4),  256, 0, stream>>>(Wvv, WvvT, 256, 2048, 1.0f);
  transpose_w<<<dim3(32, 12), 256, 0, stream>>>(Wvl, WvlT, 768, 2048, 1.0f);
  transpose_w<<<dim3(4, 32),  256, 0, stream>>>(Wov, WovT, 2048, 256, 1.0f);
  transpose_w<<<dim3(12, 32), 256, 0, stream>>>(Wol, WolT, 2048, 768, 1.0f);
  scale_bias_k<<<8, 256, 0, stream>>>(bq, bq_s, 2048, SCL);
  any_mask_k<<<8, 256, 0, stream>>>(mv, ml, anyv, anyl);

  // l-side projections (all 8 batches)
  gemm_nt<1, true><<<dim3(16, 16), 256, 0, stream>>>(l_bf, WkT,  bk,  Kw,  2048, 2048, 768, 2048);
  gemm_nt<2, true><<<dim3(16, 16), 256, 0, stream>>>(l_bf, WvlT, bvl, VlT, 2048, 2048, 768, 256);

  // ---- v-side: two groups of 4 batches
  for (int g = 0; g < 2; g++) {
    const int b0 = 4 * g;
    cvt_bf16_k<<<4096, 256, 0, stream>>>(v + (long)g * 4194304, v_bf, 1048576);
    gemm_nt<1, true><<<dim3(16, 128), 256, 0, stream>>>(v_bf, WqT,  bq_s, Qw,  16384, 2048, 256, 2048);
    gemm_nt<2, true><<<dim3(16, 128), 256, 0, stream>>>(v_bf, WvvT, bvv,  VvT, 16384, 2048, 256, 4096);
    // attn_l (split-q partials + reduce) FIRST (needs intact Qw);
    // then attn_v overwrites Qw in place with out_v
    attn_l_part<<<dim3(NSPLIT, 4, 32), 256, 0, stream>>>(Qw, Kw, VvT, mv, ml, anyv, Pp, Rp, b0);
    attn_l_red<<<dim3(4, 32), 256, 0, stream>>>(Pp, Rp, ol, b0);
    attn_v<<<dim3(64, 32), 256, 0, stream>>>(Qw, Kw, VlT, mv, ml, anyl, b0);
    // out_v projection for this group's rows
    gemm_nt<0, true><<<dim3(2, 128), 256, 0, stream>>>(Qw, WovT, bov,
        (float*)d_out + (long)g * 4194304, 16384, 256, 2048, 256);
  }

  // out_l projection (all 8 batches)
  gemm_nt<0, true><<<dim3(6, 16), 256, 0, stream>>>(ol, WolT, bol,
      (float*)d_out + 8388608, 2048, 768, 2048, 768);
}

// Round 4
// 808.338 us; speedup vs baseline: 1.4468x; 1.0195x over previous
//
#include <hip/hip_runtime.h>
#include <cstdint>

using u16 = unsigned short;
using u32 = unsigned int;

typedef short s16x8 __attribute__((ext_vector_type(8)));   // 8 bf16 (4 VGPRs)
typedef float f32x4 __attribute__((ext_vector_type(4)));

__device__ __forceinline__ u16 f2bf(float f) {  // f32 -> bf16 RNE
  u32 u = __float_as_uint(f);
  return (u16)((u + 0x7fffu + ((u >> 16) & 1u)) >> 16);
}
__device__ __forceinline__ float bf2f(u16 u) {
  return __uint_as_float(((u32)u) << 16);
}

__device__ __forceinline__ void gld16(const void* g, void* l) {
  __builtin_amdgcn_global_load_lds(
      (const __attribute__((address_space(1))) u32*)g,
      (__attribute__((address_space(3))) u32*)l, 16, 0, 0);
}

#define MFMA(a, b, c) __builtin_amdgcn_mfma_f32_16x16x32_bf16((a), (b), (c), 0, 0, 0)

// ---------------------------------------------------------------------------
// Generic NT GEMM: C[M,N] = A[M,K] @ B[N,K]^T (+bias[col])
// OUT_MODE: 0 = f32 row-major ldOut, 1 = bf16 row-major ldOut,
//           2 = bf16 transposed per-batch: out[(b*N+col)*S + (row - b*S)], S=ldOut
// 128x128 tile, BK=32, 4 waves (2x2), global_load_lds staging (m97 pattern).
// ---------------------------------------------------------------------------
template<int OUT_MODE, bool HAS_BIAS>
__global__ __launch_bounds__(256, 2)
void gemm_nt(const u16* __restrict__ A, const u16* __restrict__ B,
             const float* __restrict__ bias, void* __restrict__ C,
             int M, int N, int K, int ldOut)
{
  __shared__ __align__(16) u16 smem[17408];  // As[128*32] | Bs[128*32]; epi: ct[128][136]
  u16* As = smem;
  u16* Bs = smem + 4096;
  const int tid = threadIdx.x, wv = tid >> 6, ln = tid & 63;
  const int wm = wv >> 1, wn = wv & 1;
  const long m0 = (long)blockIdx.y * 128, n0 = (long)blockIdx.x * 128;

  f32x4 acc[4][4] = {};
  for (int k0 = 0; k0 < K; k0 += 32) {
    #pragma unroll
    for (int j = 0; j < 2; j++) {
      const int ub = j*256 + wv*64, u = ub + ln;
      gld16(A + (m0 + (u >> 2)) * K + k0 + (u & 3) * 8, As + ub * 8);
    }
    #pragma unroll
    for (int j = 0; j < 2; j++) {
      const int ub = j*256 + wv*64, u = ub + ln;
      gld16(B + (n0 + (u >> 2)) * K + k0 + (u & 3) * 8, Bs + ub * 8);
    }
    __syncthreads();
    {
      s16x8 af[4], bf[4];
      const int kk = (ln >> 4) * 8;
      #pragma unroll
      for (int i = 0; i < 4; i++) af[i] = *(const s16x8*)&As[(wm*64 + i*16 + (ln & 15)) * 32 + kk];
      #pragma unroll
      for (int i = 0; i < 4; i++) bf[i] = *(const s16x8*)&Bs[(wn*64 + i*16 + (ln & 15)) * 32 + kk];
      #pragma unroll
      for (int i = 0; i < 4; i++)
        #pragma unroll
        for (int j = 0; j < 4; j++)
          acc[i][j] = MFMA(af[i], bf[j], acc[i][j]);
    }
    __syncthreads();
  }

  if constexpr (OUT_MODE == 2) {
    u16* ct = smem;  // [128 col][136 row] bf16
    #pragma unroll
    for (int i = 0; i < 4; i++)
      #pragma unroll
      for (int j = 0; j < 4; j++)
        #pragma unroll
        for (int jj = 0; jj < 4; jj++) {
          const int cl = wn*64 + j*16 + (ln & 15);
          const int rl = wm*64 + i*16 + (ln >> 4) * 4 + jj;
          float v = acc[i][j][jj];
          if constexpr (HAS_BIAS) v += bias[n0 + cl];
          ct[cl * 136 + rl] = f2bf(v);
        }
    __syncthreads();
    const long S = ldOut;
    const long bb = m0 / S;                 // batch index (tile never crosses: S % 128 == 0)
    u16* T = (u16*)C + bb * (long)(N - 1) * S;
    #pragma unroll
    for (int t = 0; t < 8; t++) {
      const int u = t*256 + tid;
      const int cl = u >> 4, r8 = (u & 15) * 8;
      *(s16x8*)&T[(n0 + cl) * S + (m0 + r8)] = *(const s16x8*)&ct[cl * 136 + r8];
    }
  } else {
    #pragma unroll
    for (int i = 0; i < 4; i++)
      #pragma unroll
      for (int jj = 0; jj < 4; jj++) {
        const long r = m0 + wm*64 + i*16 + (ln >> 4) * 4 + jj;
        #pragma unroll
        for (int j = 0; j < 4; j++) {
          const long col = n0 + wn*64 + j*16 + (ln & 15);
          float v = acc[i][j][jj];
          if constexpr (HAS_BIAS) v += bias[col];
          if constexpr (OUT_MODE == 0) ((float*)C)[r * ldOut + col] = v;
          else                         ((u16*)C)[r * ldOut + col] = f2bf(v);
        }
      }
  }
}

// ---------------------------------------------------------------------------
// Pass 1 (per batch-group of 4): per (b,h, 64-row q-tile): S = Q@K^T,
// row softmax over Hl=256 (mask-shift trick), out_v = P @ VlT^T.
// Writes out IN PLACE over this block's own Q slice. attn_l_part runs first.
// ---------------------------------------------------------------------------
__global__ __launch_bounds__(256, 2)
void attn_v(u16* __restrict__ Q, const u16* __restrict__ Kw,
            const u16* __restrict__ VlT, const int* __restrict__ mask_v,
            const int* __restrict__ mask_l, const int* __restrict__ anylp,
            int b_base)
{
  __shared__ __align__(16) u16 As[64*72];
  __shared__ __align__(16) u16 Bs[256*72];
  __shared__ __align__(16) u16 Ps[64*264];
  __shared__ float red[256];

  const int qt = blockIdx.x;
  const int bl = blockIdx.y >> 3, h = blockIdx.y & 7;
  const int b = b_base + bl;
  const int tid = threadIdx.x, wv = tid >> 6, ln = tid & 63;

  u16* Qb = Q + (long)(bl*4096 + qt*64) * 2048 + h*256;     // group-local
  const u16* Kb = Kw + (long)(b*256) * 2048 + h*256;        // global
  const u16* Vb = VlT + (long)(b*8 + h) * 65536;            // global

  const int al = anylp[b];
  float mlf[4], rf[4][4];
  #pragma unroll
  for (int j = 0; j < 4; j++)
    mlf[j] = mask_l[b*256 + wv*64 + j*16 + (ln & 15)] ? 1.f : 0.f;
  #pragma unroll
  for (int i = 0; i < 4; i++)
    #pragma unroll
    for (int jj = 0; jj < 4; jj++)
      rf[i][jj] = (al && mask_v[b*4096 + qt*64 + i*16 + (ln >> 4)*4 + jj]) ? 1.f : 0.f;

  // ---- S = Q @ K^T : [64 q][256 k], wave owns k-slice wv*64
  f32x4 acc[4][4] = {};
  for (int d0 = 0; d0 < 256; d0 += 64) {
    #pragma unroll
    for (int j = 0; j < 2; j++) {
      const int u = j*256 + tid, r = u >> 3, c = (u & 7) * 8;
      *(s16x8*)&As[r*72 + c] = *(const s16x8*)(Qb + (long)r*2048 + d0 + c);
    }
    #pragma unroll
    for (int j = 0; j < 8; j++) {
      const int u = j*256 + tid, r = u >> 3, c = (u & 7) * 8;
      *(s16x8*)&Bs[r*72 + c] = *(const s16x8*)(Kb + (long)r*2048 + d0 + c);
    }
    __syncthreads();
    #pragma unroll
    for (int ks = 0; ks < 2; ks++) {
      s16x8 af[4], bf[4];
      const int kk = ks*32 + (ln >> 4) * 8;
      #pragma unroll
      for (int i = 0; i < 4; i++) af[i] = *(const s16x8*)&As[(i*16 + (ln & 15))*72 + kk];
      #pragma unroll
      for (int j = 0; j < 4; j++) bf[j] = *(const s16x8*)&Bs[(wv*64 + j*16 + (ln & 15))*72 + kk];
      #pragma unroll
      for (int i = 0; i < 4; i++)
        #pragma unroll
        for (int j = 0; j < 4; j++)
          acc[i][j] = MFMA(af[i], bf[j], acc[i][j]);
    }
    __syncthreads();
  }

  // ---- row softmax (mask-shift trick: E = rf ? maskl*exp(S) : 1)
  #pragma unroll
  for (int i = 0; i < 4; i++)
    #pragma unroll
    for (int j = 0; j < 4; j++)
      #pragma unroll
      for (int jj = 0; jj < 4; jj++) {
        const float s = acc[i][j][jj];
        acc[i][j][jj] = (rf[i][jj] != 0.f) ? mlf[j] * __expf(s) : 1.0f;
      }
  #pragma unroll
  for (int i = 0; i < 4; i++)
    #pragma unroll
    for (int jj = 0; jj < 4; jj++) {
      float t = acc[i][0][jj] + acc[i][1][jj] + acc[i][2][jj] + acc[i][3][jj];
      t += __shfl_xor(t, 1); t += __shfl_xor(t, 2);
      t += __shfl_xor(t, 4); t += __shfl_xor(t, 8);
      if ((ln & 15) == 0) red[wv*64 + i*16 + (ln >> 4)*4 + jj] = t;
    }
  __syncthreads();
  float inv[4][4];
  #pragma unroll
  for (int i = 0; i < 4; i++)
    #pragma unroll
    for (int jj = 0; jj < 4; jj++) {
      const int r = i*16 + (ln >> 4)*4 + jj;
      inv[i][jj] = 1.0f / (red[r] + red[64 + r] + red[128 + r] + red[192 + r]);
    }
  #pragma unroll
  for (int i = 0; i < 4; i++)
    #pragma unroll
    for (int j = 0; j < 4; j++)
      #pragma unroll
      for (int jj = 0; jj < 4; jj++)
        Ps[(i*16 + (ln >> 4)*4 + jj)*264 + wv*64 + j*16 + (ln & 15)] =
            f2bf(acc[i][j][jj] * inv[i][jj]);
  __syncthreads();

  // ---- out_v = P @ VlT^T : [64 q][256 d], wave owns d-slice wv*64
  f32x4 acc2[4][4] = {};
  for (int c0 = 0; c0 < 256; c0 += 64) {
    #pragma unroll
    for (int j = 0; j < 8; j++) {
      const int u = j*256 + tid, r = u >> 3, c = (u & 7) * 8;
      *(s16x8*)&Bs[r*72 + c] = *(const s16x8*)(Vb + (long)r*256 + c0 + c);
    }
    __syncthreads();
    #pragma unroll
    for (int ks = 0; ks < 2; ks++) {
      s16x8 af[4], bf[4];
      const int kk = ks*32 + (ln >> 4) * 8;
      #pragma unroll
      for (int i = 0; i < 4; i++) af[i] = *(const s16x8*)&Ps[(i*16 + (ln & 15))*264 + c0 + kk];
      #pragma unroll
      for (int j = 0; j < 4; j++) bf[j] = *(const s16x8*)&Bs[(wv*64 + j*16 + (ln & 15))*72 + kk];
      #pragma unroll
      for (int i = 0; i < 4; i++)
        #pragma unroll
        for (int j = 0; j < 4; j++)
          acc2[i][j] = MFMA(af[i], bf[j], acc2[i][j]);
    }
    __syncthreads();
  }
  // in-place store over own Q slice
  #pragma unroll
  for (int i = 0; i < 4; i++)
    #pragma unroll
    for (int j = 0; j < 4; j++)
      #pragma unroll
      for (int jj = 0; jj < 4; jj++)
        Qb[(long)(i*16 + (ln >> 4)*4 + jj)*2048 + wv*64 + j*16 + (ln & 15)] =
            f2bf(acc2[i][j][jj]);
}

// ---------------------------------------------------------------------------
// Pass 2a (split-q partials), register-fragment version:
// grid (split s=0..7, kt=0..3, bh=0..31). Block owns K-tile [64 k] x 512 q.
// Q and V operands are wave-exclusive rows -> direct global->reg fragments
// (no LDS staging, no staging barriers). Only E bounces through LDS.
// 2 barriers per 64-q chunk.
// ---------------------------------------------------------------------------
#define NSPLIT 8
__global__ __launch_bounds__(256, 3)
void attn_l_part(const u16* __restrict__ Q, const u16* __restrict__ Kw,
                 const u16* __restrict__ VvT, const int* __restrict__ mask_v,
                 const int* __restrict__ mask_l, const int* __restrict__ anyvp,
                 u16* __restrict__ Pp, float* __restrict__ Rp, int b_base)
{
  __shared__ __align__(16) u16 Ks[64*264];   // 33792 B
  __shared__ __align__(16) u16 Es[64*72];    //  9216 B
  __shared__ float red[256];                 //  1024 B   (total ~44 KB -> 3 blk/CU)

  const int sp = blockIdx.x, kt = blockIdx.y;
  const int bl = blockIdx.z >> 3, h = blockIdx.z & 7;
  const int b = b_base + bl;
  const int tid = threadIdx.x, wv = tid >> 6, ln = tid & 63;
  const int l = ln & 15, g = ln >> 4;

  const u16* Qb  = Q + (long)(bl*4096) * 2048 + h*256;            // group-local
  const u16* Kb  = Kw + (long)(b*256 + kt*64) * 2048 + h*256;     // global
  const u16* Vvb = VvT + (long)(bl*8 + h) * (256L*4096);          // group-local

  // stage K tile [64][256] -> Ks (loop-invariant)
  #pragma unroll
  for (int j = 0; j < 8; j++) {
    const int u = j*256 + tid, r = u >> 5, c = (u & 31) * 8;
    *(s16x8*)&Ks[r*264 + c] = *(const s16x8*)(Kb + (long)r*2048 + c);
  }
  const int av = anyvp[b];
  u32 cmask = 0;
  #pragma unroll
  for (int i = 0; i < 4; i++)
    #pragma unroll
    for (int jj = 0; jj < 4; jj++)
      if (av && mask_l[b*256 + kt*64 + i*16 + g*4 + jj]) cmask |= 1u << (i*4 + jj);

  float rsum[4][4] = {};
  f32x4 pacc[4][4] = {};
  __syncthreads();   // Ks visible

  const int qlo = sp * (4096 / NSPLIT), qhi = qlo + 4096 / NSPLIT;
  #pragma unroll 1
  for (int qc = qlo; qc < qhi; qc += 64) {
    // per-lane column mask (col q = qc + wv*16 + l)
    const float mvf = mask_v[b*4096 + qc + wv*16 + l] ? 1.f : 0.f;

    // ---- Q fragments direct global->reg (wave-exclusive rows wv*16+l)
    s16x8 qf[4][2];
    #pragma unroll
    for (int d0 = 0; d0 < 4; d0++)
      #pragma unroll
      for (int ks = 0; ks < 2; ks++)
        qf[d0][ks] = *(const s16x8*)(Qb + (long)(qc + wv*16 + l)*2048 + d0*64 + ks*32 + g*8);

    // ---- S^T chunk [64 k][16 q per wave], no barriers
    f32x4 sacc[4] = {};
    #pragma unroll
    for (int d0 = 0; d0 < 4; d0++)
      #pragma unroll
      for (int ks = 0; ks < 2; ks++) {
        const int kk = d0*64 + ks*32 + g*8;
        #pragma unroll
        for (int i = 0; i < 4; i++)
          sacc[i] = MFMA(*(const s16x8*)&Ks[(i*16 + l)*264 + kk], qf[d0][ks], sacc[i]);
      }

    // ---- V fragments direct global->reg (wave-exclusive d-rows wv*64+j*16+l);
    // latency hides under E-phase + barrier
    s16x8 vf[4][2];
    #pragma unroll
    for (int j = 0; j < 4; j++)
      #pragma unroll
      for (int ks = 0; ks < 2; ks++)
        vf[j][ks] = *(const s16x8*)(Vvb + (long)(wv*64 + j*16 + l)*4096 + qc + ks*32 + g*8);

    // ---- E = colflag ? mvf*exp(S) : 1 ; rowsum; bounce E^T slice to LDS
    #pragma unroll
    for (int i = 0; i < 4; i++)
      #pragma unroll
      for (int jj = 0; jj < 4; jj++) {
        const float x = ((cmask >> (i*4 + jj)) & 1) ? mvf * __expf(sacc[i][jj]) : 1.0f;
        float t = x;
        t += __shfl_xor(t, 1); t += __shfl_xor(t, 2);
        t += __shfl_xor(t, 4); t += __shfl_xor(t, 8);
        rsum[i][jj] += t;
        Es[(i*16 + g*4 + jj)*72 + wv*16 + l] = f2bf(x);
      }
    __syncthreads();   // E visible for PV

    // ---- pacc += E @ vf^T
    #pragma unroll
    for (int ks = 0; ks < 2; ks++) {
      s16x8 ae[4];
      const int kk = ks*32 + g*8;
      #pragma unroll
      for (int i = 0; i < 4; i++) ae[i] = *(const s16x8*)&Es[(i*16 + l)*72 + kk];
      #pragma unroll
      for (int i = 0; i < 4; i++)
        #pragma unroll
        for (int j = 0; j < 4; j++)
          pacc[i][j] = MFMA(ae[i], vf[j][ks], pacc[i][j]);
    }
    __syncthreads();   // protect Es for next chunk's writes
  }

  // ---- write partials
  const long unit = ((long)blockIdx.z * 4 + kt) * NSPLIT + sp;
  u16*   Pb = Pp + unit * 16384;   // [64 k][256 d] bf16
  float* Rb = Rp + unit * 64;      // [64 k] f32
  #pragma unroll
  for (int i = 0; i < 4; i++)
    #pragma unroll
    for (int jj = 0; jj < 4; jj++)
      if (l == 0) red[wv*64 + i*16 + g*4 + jj] = rsum[i][jj];
  __syncthreads();
  if (tid < 64) Rb[tid] = red[tid] + red[64 + tid] + red[128 + tid] + red[192 + tid];
  #pragma unroll
  for (int i = 0; i < 4; i++)
    #pragma unroll
    for (int jj = 0; jj < 4; jj++) {
      const int r = i*16 + g*4 + jj;
      #pragma unroll
      for (int j = 0; j < 4; j++)
        Pb[r*256 + wv*64 + j*16 + l] = f2bf(pacc[i][j][jj]);
    }
}

// ---------------------------------------------------------------------------
// Pass 2b (reduce): grid (kt=0..3, bh=0..31). Sums NSPLIT partials,
// normalizes by total rowsum, writes ol[(b*256+k)*2048 + h*256+d] bf16.
// ---------------------------------------------------------------------------
__global__ __launch_bounds__(256, 4)
void attn_l_red(const u16* __restrict__ Pp, const float* __restrict__ Rp,
                u16* __restrict__ ol, int b_base)
{
  __shared__ float rt[64];
  const int kt = blockIdx.x;
  const int bl = blockIdx.y >> 3, h = blockIdx.y & 7;
  const int b = b_base + bl;
  const int tid = threadIdx.x;
  const long ub = ((long)blockIdx.y * 4 + kt) * NSPLIT;

  if (tid < 64) {
    float t = 0.f;
    #pragma unroll
    for (int s = 0; s < NSPLIT; s++) t += Rp[(ub + s) * 64 + tid];
    rt[tid] = 1.0f / t;
  }
  __syncthreads();

  u16* olb = ol + (long)(b*256 + kt*64) * 2048 + h*256;
  #pragma unroll
  for (int it = 0; it < 8; it++) {
    const int idx = it*256 + tid;           // 0..2047 -> (r, 8-wide d chunk)
    const int r = idx >> 5, c8 = (idx & 31) * 8;
    float a[8] = {};
    #pragma unroll
    for (int s = 0; s < NSPLIT; s++) {
      const s16x8 p = *(const s16x8*)&Pp[(ub + s)*16384 + r*256 + c8];
      #pragma unroll
      for (int e = 0; e < 8; e++) a[e] += bf2f((u16)p[e]);
    }
    const float sc = rt[r];
    s16x8 o;
    #pragma unroll
    for (int e = 0; e < 8; e++) o[e] = (short)f2bf(a[e] * sc);
    *(s16x8*)&olb[(long)r*2048 + c8] = o;
  }
}

// ---------------------------------------------------------------------------
// small utility kernels
// ---------------------------------------------------------------------------
__global__ void cvt_bf16_k(const float* __restrict__ x, u16* __restrict__ y, long n4) {
  const long i = (long)blockIdx.x * 256 + threadIdx.x;
  if (i < n4) {
    const float4 v = ((const float4*)x)[i];
    u32 lo = (u32)f2bf(v.x) | ((u32)f2bf(v.y) << 16);
    u32 hi = (u32)f2bf(v.z) | ((u32)f2bf(v.w) << 16);
    ((uint2*)y)[i] = make_uint2(lo, hi);
  }
}

__global__ void transpose_w(const float* __restrict__ W, u16* __restrict__ WT,
                            int K, int N, float scale) {
  __shared__ float t[64][65];
  const int k0 = blockIdx.y * 64, n0 = blockIdx.x * 64;
  const int tid = threadIdx.x;
  #pragma unroll
  for (int i = 0; i < 16; i++) {
    const int u = i*256 + tid, r = u >> 6, c = u & 63;
    t[r][c] = W[(long)(k0 + r) * N + n0 + c];
  }
  __syncthreads();
  #pragma unroll
  for (int i = 0; i < 16; i++) {
    const int u = i*256 + tid, r = u >> 6, c = u & 63;
    WT[(long)(n0 + r) * K + k0 + c] = f2bf(t[c][r] * scale);
  }
}

__global__ void scale_bias_k(const float* __restrict__ x, float* __restrict__ y,
                             int n, float s) {
  const int i = blockIdx.x * 256 + threadIdx.x;
  if (i < n) y[i] = x[i] * s;
}

__global__ void any_mask_k(const int* __restrict__ mv, const int* __restrict__ ml,
                           int* __restrict__ anyv, int* __restrict__ anyl) {
  __shared__ int s[256];
  const int b = blockIdx.x, t = threadIdx.x;
  int a = 0;
  for (int i = t; i < 4096; i += 256) a |= mv[b*4096 + i];
  s[t] = a; __syncthreads();
  for (int o = 128; o > 0; o >>= 1) { if (t < o) s[t] |= s[t + o]; __syncthreads(); }
  if (t == 0) anyv[b] = s[0] ? 1 : 0;
  __syncthreads();
  s[t] = ml[b*256 + t]; __syncthreads();
  for (int o = 128; o > 0; o >>= 1) { if (t < o) s[t] |= s[t + o]; __syncthreads(); }
  if (t == 0) anyl[b] = s[0] ? 1 : 0;
}

// ---------------------------------------------------------------------------
extern "C" void kernel_launch(void* const* d_in, const int* in_sizes, int n_in,
                              void* d_out, int out_size, void* d_ws, size_t ws_size,
                              hipStream_t stream)
{
  (void)in_sizes; (void)n_in; (void)out_size; (void)ws_size;
  const float* v   = (const float*)d_in[0];
  const float* l   = (const float*)d_in[1];
  const int*   mv  = (const int*)d_in[2];
  const int*   ml  = (const int*)d_in[3];
  const float* Wq  = (const float*)d_in[4];
  const float* bq  = (const float*)d_in[5];
  const float* Wk  = (const float*)d_in[6];
  const float* bk  = (const float*)d_in[7];
  const float* Wvv = (const float*)d_in[8];
  const float* bvv = (const float*)d_in[9];
  const float* Wvl = (const float*)d_in[10];
  const float* bvl = (const float*)d_in[11];
  const float* Wov = (const float*)d_in[12];
  const float* bov = (const float*)d_in[13];
  const float* Wol = (const float*)d_in[14];
  const float* bol = (const float*)d_in[15];

  char* w = (char*)d_ws;
  auto alloc = [&](size_t bytes) { char* p = w; w += (bytes + 255) & ~(size_t)255; return p; };
  // global (both groups):
  u16*   l_bf = (u16*)alloc(1572864ull * 2);
  u16*   WqT  = (u16*)alloc(2048ull*256*2);
  u16*   WkT  = (u16*)alloc(2048ull*768*2);
  u16*   WvvT = (u16*)alloc(2048ull*256*2);
  u16*   WvlT = (u16*)alloc(2048ull*768*2);
  u16*   WovT = (u16*)alloc(256ull*2048*2);
  u16*   WolT = (u16*)alloc(768ull*2048*2);
  float* bq_s = (float*)alloc(2048*4);
  int*   anyv = (int*)alloc(256);
  int*   anyl = (int*)alloc(256);
  u16*   Kw   = (u16*)alloc(4194304ull * 2);               //  [b*256+k][2048]
  u16*   VlT  = (u16*)alloc(4194304ull * 2);               //  [b,h,d=256][k=256]
  u16*   ol   = (u16*)alloc(4194304ull * 2);               //  [b*256+k][2048]
  // per-group (4 batches), reused across the 2 groups:
  u16*   v_bf = (u16*)alloc(4194304ull * 2);               //  [16384][256]
  u16*   Qw   = (u16*)alloc(33554432ull * 2);              //  [16384][2048]; becomes ov in place
  u16*   VvT  = (u16*)alloc(33554432ull * 2);              //  [bl,h,d=256][q=4096]
  u16*   Pp   = (u16*)alloc((size_t)32*4*NSPLIT*16384*2);  //  33.6M partial pacc
  float* Rp   = (float*)alloc((size_t)32*4*NSPLIT*64*4);   //  0.26M partial rowsum

  const float SCL = 0.0625f;  // 256^-0.5

  // ---- setup (l-side + weights), once
  cvt_bf16_k<<<1536, 256, 0, stream>>>(l, l_bf, 393216);
  transpose_w<<<dim3(32, 4),  256, 0, stream>>>(Wq,  WqT,  256, 2048, SCL);
  transpose_w<<<dim3(32, 12), 256, 0, stream>>>(Wk,  WkT,  768, 2048, 1.0f);
  transpose_w<<<dim3(32, 4),  256, 0, stream>>>(Wvv, WvvT, 256, 2048, 1.0f);
  transpose_w<<<dim3(32, 12), 256, 0, stream>>>(Wvl, WvlT, 768, 2048, 1.0f);
  transpose_w<<<dim3(4, 32),  256, 0, stream>>>(Wov, WovT, 2048, 256, 1.0f);
  transpose_w<<<dim3(12, 32), 256, 0, stream>>>(Wol, WolT, 2048, 768, 1.0f);
  scale_bias_k<<<8, 256, 0, stream>>>(bq, bq_s, 2048, SCL);
  any_mask_k<<<8, 256, 0, stream>>>(mv, ml, anyv, anyl);

  // l-side projections (all 8 batches)
  gemm_nt<1, true><<<dim3(16, 16), 256, 0, stream>>>(l_bf, WkT,  bk,  Kw,  2048, 2048, 768, 2048);
  gemm_nt<2, true><<<dim3(16, 16), 256, 0, stream>>>(l_bf, WvlT, bvl, VlT, 2048, 2048, 768, 256);

  // ---- v-side: two groups of 4 batches
  for (int g = 0; g < 2; g++) {
    const int b0 = 4 * g;
    cvt_bf16_k<<<4096, 256, 0, stream>>>(v + (long)g * 4194304, v_bf, 1048576);
    gemm_nt<1, true><<<dim3(16, 128), 256, 0, stream>>>(v_bf, WqT,  bq_s, Qw,  16384, 2048, 256, 2048);
    gemm_nt<2, true><<<dim3(16, 128), 256, 0, stream>>>(v_bf, WvvT, bvv,  VvT, 16384, 2048, 256, 4096);
    // attn_l (split-q partials + reduce) FIRST (needs intact Qw);
    // then attn_v overwrites Qw in place with out_v
    attn_l_part<<<dim3(NSPLIT, 4, 32), 256, 0, stream>>>(Qw, Kw, VvT, mv, ml, anyv, Pp, Rp, b0);
    attn_l_red<<<dim3(4, 32), 256, 0, stream>>>(Pp, Rp, ol, b0);
    attn_v<<<dim3(64, 32), 256, 0, stream>>>(Qw, Kw, VlT, mv, ml, anyl, b0);
    // out_v projection for this group's rows
    gemm_nt<0, true><<<dim3(2, 128), 256, 0, stream>>>(Qw, WovT, bov,
        (float*)d_out + (long)g * 4194304, 16384, 256, 2048, 256);
  }

  // out_l projection (all 8 batches)
  gemm_nt<0, true><<<dim3(6, 16), 256, 0, stream>>>(ol, WolT, bol,
      (float*)d_out + 8388608, 2048, 768, 2048, 768);
}